// Round 2
// baseline (420.760 us; speedup 1.0000x reference)
//
#include <hip/hip_runtime.h>
#include <math.h>

#define TOKENS 16384
#define DIM    4096
#define NEXP   64
#define KSPLIT 4
#define KSLICE (DIM / KSPLIT)   // 1024
#define BK     32               // k per chunk (one MFMA K=32 worth of fp16 pairs)
#define NCHUNK (KSLICE / BK)    // 32
#define NCHUNK_G (DIM / BK)     // 128 global chunks (pack kernel covers full K)

typedef _Float16 f16x8 __attribute__((ext_vector_type(8)));
typedef float    f32x4 __attribute__((ext_vector_type(4)));

#define MFMA16(a, b, c) __builtin_amdgcn_mfma_f32_16x16x32_f16((a), (b), (c), 0, 0, 0)

// ---------------- Kernel 0: pack W into MFMA B-fragments (fp16 hi/lo split) ----
// Layout: wpk[c=0..127][t=0..3][lane=0..63][2] x 16B frags (hi, lo).
// Fragment convention (must match A-side in the GEMM): lane l supplies
// B[k = 8*(l>>4)+j][n = l&15] for j=0..7. Any HW-internal k-permutation cancels
// because A uses the same convention. Lo part scaled by 2^16 so it stays
// fp16-normal; |w|<2^-14 guarded to 0 in hi so denormal-flush can't bite.
__global__ __launch_bounds__(256)
void pack_w_kernel(const float* __restrict__ w, uint4* __restrict__ wpk) {
    const int lane = threadIdx.x & 63;
    const int t    = threadIdx.x >> 6;     // expert tile 0..3
    const int c    = blockIdx.x;           // global k-chunk 0..127
    const int e    = 16 * t + (lane & 15);
    const int k0   = 32 * c + 8 * (lane >> 4);

    const float* src = w + (size_t)e * DIM + k0;
    const float4 v0 = *(const float4*)(src);
    const float4 v1 = *(const float4*)(src + 4);
    const float xs[8] = {v0.x, v0.y, v0.z, v0.w, v1.x, v1.y, v1.z, v1.w};

    f16x8 hi, lo;
#pragma unroll
    for (int j = 0; j < 8; ++j) {
        const float xv = xs[j];
        _Float16 h = (_Float16)xv;           // RNE
        float hf = (float)h;
        if (fabsf(xv) < 6.103515625e-05f) {  // below fp16 min normal: force hi=0
            h = (_Float16)0.f; hf = 0.f;
        }
        hi[j] = h;
        lo[j] = (_Float16)((xv - hf) * 65536.f);  // exact sub; scaled lo is normal
    }

    uint4* dst = wpk + ((size_t)(c * 4 + t) * 64 + lane) * 2;
    dst[0] = *(const uint4*)&hi;
    dst[1] = *(const uint4*)&lo;
}

// ---------------- Kernel 1: split-K router GEMM via fp16-split MFMA ----------
// grid 1024, block 256 (4 waves, no LDS/barriers). ks = bid&3: co-resident
// blocks (bid+=256) share one W k-slice -> B stream is L1/L2-resident.
//
// R2 change: FIFO load pipeline so the compiler emits COUNTED s_waitcnt
// vmcnt(N), never vmcnt(0). Round-1 loaded B frags and consumed them
// immediately -> waiting on the NEWEST loads == vmcnt(0) == drains the X
// prefetch queue every chunk (vmcnt retires in order). That serialized every
// chunk on an L2 round-trip and collapsed X to ~1-chunk depth (~2 TB/s
// effective DRAM rate). Now:
//   - B double-buffered in regs, refilled per HALF-chunk right after its
//     consumption -> consume always has 6-10 newer loads outstanding.
//   - X ping-pong (2 bufs), refill issued immediately after split_a frees the
//     buffer -> ~2 chunk-walls (~1900 cyc) of lead > 900 cyc HBM latency.
// B over-the-end prefetch (chunk 32/33) lands in the 1 GB workspace: safe.
// X prefetch is guarded branchlessly (wraps to chunk 0).
__device__ __forceinline__ void split_a(const float4 lo, const float4 hi,
                                        f16x8& ah, f16x8& al) {
    const float xs[8] = {lo.x, lo.y, lo.z, lo.w, hi.x, hi.y, hi.z, hi.w};
#pragma unroll
    for (int j = 0; j < 8; ++j) {
        const float xv = xs[j];
        const _Float16 h = (_Float16)xv;               // RNE
        ah[j] = h;
        al[j] = (_Float16)((xv - (float)h) * 65536.f); // exact sub, exact *2^16
    }
}

__device__ __forceinline__ void fma3(const f16x8 ah, const f16x8 al,
                                     const f16x8 bh, const f16x8 bl,
                                     f32x4& a1, f32x4& a2) {
    a1 = MFMA16(ah, bh, a1);   // hi*hi
    a2 = MFMA16(ah, bl, a2);   // hi*lo (scaled 2^16)
    a2 = MFMA16(al, bh, a2);   // lo*hi (scaled 2^16)
}

__global__ __launch_bounds__(256)
__attribute__((amdgpu_waves_per_eu(4, 4)))
void router_gemm_kernel(const float* __restrict__ x,
                        const f16x8* __restrict__ wpk,
                        float* __restrict__ part) {
    const int tid    = threadIdx.x;
    const int lane   = tid & 63;
    const int wv     = tid >> 6;
    const int bid    = blockIdx.x;
    const int ks     = bid & (KSPLIT - 1);
    const int tb     = bid >> 2;
    const int token0 = tb * 64 + wv * 16;

    // A side: lane l -> token row (l&15), k base 8*(l>>4) within the chunk
    const int row = token0 + (lane & 15);
    const float* xp = x + (size_t)row * DIM + ks * KSLICE + 8 * (lane >> 4);

    // B side: per-chunk stride 512 f16x8; tile stride 128; (hi,lo) adjacent
    const f16x8* bp = wpk + (size_t)ks * NCHUNK * 512 + lane * 2;

    f32x4 a10, a11, a12, a13, a20, a21, a22, a23;
    const f32x4 zero = {0.f, 0.f, 0.f, 0.f};
    a10 = a11 = a12 = a13 = zero;
    a20 = a21 = a22 = a23 = zero;

    // prologue: X chunks 0,1; B chunk 0 (all 4 tiles)
    float4 xAlo = *(const float4*)(xp);
    float4 xAhi = *(const float4*)(xp + 4);
    float4 xBlo = *(const float4*)(xp + BK);
    float4 xBhi = *(const float4*)(xp + BK + 4);
    f16x8 bh0 = bp[0],   bl0 = bp[1];
    f16x8 bh1 = bp[128], bl1 = bp[129];
    f16x8 bh2 = bp[256], bl2 = bp[257];
    f16x8 bh3 = bp[384], bl3 = bp[385];

    f16x8 ah, al;
#pragma unroll 1
    for (int c = 0; c < NCHUNK; c += 2) {
        // ---------------- chunk c (X in xA, B in bh*/bl*) ----------------
        split_a(xAlo, xAhi, ah, al);
        {   // X refill -> chunk c+2 (issued early: xA is free after split)
            const int cn = (c + 2 < NCHUNK) ? c + 2 : 0;
            xAlo = *(const float4*)(xp + cn * BK);
            xAhi = *(const float4*)(xp + cn * BK + 4);
        }
        fma3(ah, al, bh0, bl0, a10, a20);
        fma3(ah, al, bh1, bl1, a11, a21);
        {   // refill tiles 0,1 <- chunk c+1
            const f16x8* pn = bp + (size_t)(c + 1) * 512;
            bh0 = pn[0]; bl0 = pn[1]; bh1 = pn[128]; bl1 = pn[129];
        }
        fma3(ah, al, bh2, bl2, a12, a22);
        fma3(ah, al, bh3, bl3, a13, a23);
        {   // refill tiles 2,3 <- chunk c+1
            const f16x8* pn = bp + (size_t)(c + 1) * 512;
            bh2 = pn[256]; bl2 = pn[257]; bh3 = pn[384]; bl3 = pn[385];
        }
        // ---------------- chunk c+1 (X in xB) ----------------
        split_a(xBlo, xBhi, ah, al);
        {   // X refill -> chunk c+3
            const int cn = (c + 3 < NCHUNK) ? c + 3 : 0;
            xBlo = *(const float4*)(xp + cn * BK);
            xBhi = *(const float4*)(xp + cn * BK + 4);
        }
        fma3(ah, al, bh0, bl0, a10, a20);
        fma3(ah, al, bh1, bl1, a11, a21);
        {   // refill tiles 0,1 <- chunk c+2 (c=30: overread into ws, safe)
            const f16x8* pn = bp + (size_t)(c + 2) * 512;
            bh0 = pn[0]; bl0 = pn[1]; bh1 = pn[128]; bl1 = pn[129];
        }
        fma3(ah, al, bh2, bl2, a12, a22);
        fma3(ah, al, bh3, bl3, a13, a23);
        {   // refill tiles 2,3 <- chunk c+2
            const f16x8* pn = bp + (size_t)(c + 2) * 512;
            bh2 = pn[256]; bl2 = pn[257]; bh3 = pn[384]; bl3 = pn[385];
        }
    }

    // Epilogue: D lane map (HW-verified): m = 4*(l>>4)+r, n = l&15.
    float* pout = part + ((size_t)ks * TOKENS + token0 + 4 * (lane >> 4)) * NEXP
                + (lane & 15);
    const f32x4 v0 = a10 + a20 * (1.f / 65536.f);
    const f32x4 v1 = a11 + a21 * (1.f / 65536.f);
    const f32x4 v2 = a12 + a22 * (1.f / 65536.f);
    const f32x4 v3 = a13 + a23 * (1.f / 65536.f);
#pragma unroll
    for (int r = 0; r < 4; ++r) {
        pout[(size_t)r * NEXP +  0] = v0[r];
        pout[(size_t)r * NEXP + 16] = v1[r];
        pout[(size_t)r * NEXP + 32] = v2[r];
        pout[(size_t)r * NEXP + 48] = v3[r];
    }
}

// ---------------- Kernel 2: split-K reduce + top-2 + softmax ----------------
// One wave per token; lane == expert. Butterfly argmax twice (tiebreak: lower
// index). Indices written as float (harness reads d_out via the fp32 path).
__global__ __launch_bounds__(256)
void topk_kernel(const float* __restrict__ part, float* __restrict__ out) {
    const int lane  = threadIdx.x & 63;
    const int wv    = threadIdx.x >> 6;
    const int token = blockIdx.x * 4 + wv;

    float logit = 0.f;
#pragma unroll
    for (int s = 0; s < KSPLIT; ++s)
        logit += part[((size_t)s * TOKENS + token) * NEXP + lane];

    // top-1
    float v1 = logit; int i1 = lane;
#pragma unroll
    for (int off = 32; off > 0; off >>= 1) {
        const float ov = __shfl_xor(v1, off);
        const int   oi = __shfl_xor(i1, off);
        if (ov > v1 || (ov == v1 && oi < i1)) { v1 = ov; i1 = oi; }
    }
    // top-2: mask the winner
    float v2 = (lane == i1) ? -INFINITY : logit; int i2 = lane;
#pragma unroll
    for (int off = 32; off > 0; off >>= 1) {
        const float ov = __shfl_xor(v2, off);
        const int   oi = __shfl_xor(i2, off);
        if (ov > v2 || (ov == v2 && oi < i2)) { v2 = ov; i2 = oi; }
    }

    if (lane == 0) {
        const float e = expf(v2 - v1);       // <= 1, no overflow
        const float r = 1.f / (1.f + e);
        out[2 * token + 0] = r;              // score of top-1
        out[2 * token + 1] = e * r;          // score of top-2
        out[2 * TOKENS + 2 * token + 0] = (float)i1;
        out[2 * TOKENS + 2 * token + 1] = (float)i2;
    }
}

extern "C" void kernel_launch(void* const* d_in, const int* in_sizes, int n_in,
                              void* d_out, int out_size, void* d_ws, size_t ws_size,
                              hipStream_t stream) {
    const float* x = (const float*)d_in[0];   // (4,4096,4096) fp32
    const float* w = (const float*)d_in[1];   // (64,4096) fp32
    float* out  = (float*)d_out;              // 32768 scores + 32768 float-encoded indices
    float* part = (float*)d_ws;               // KSPLIT*TOKENS*NEXP*4 = 16.8 MB
    // packed W fragments right after part: 128*4*64*2*16B = 1 MB
    uint4* wpk = (uint4*)((char*)d_ws + (size_t)KSPLIT * TOKENS * NEXP * sizeof(float));

    pack_w_kernel<<<NCHUNK_G, 256, 0, stream>>>(w, wpk);
    router_gemm_kernel<<<(TOKENS / 64) * KSPLIT, 256, 0, stream>>>(
        x, (const f16x8*)wpk, part);
    topk_kernel<<<TOKENS / 4, 256, 0, stream>>>(part, out);
}

// Round 4
// 408.588 us; speedup vs baseline: 1.0298x; 1.0298x over previous
//
#include <hip/hip_runtime.h>
#include <math.h>

#define TOKENS 16384
#define DIM    4096
#define NEXP   64
#define KSPLIT 4
#define KSLICE (DIM / KSPLIT)   // 1024
#define BK     32               // k per chunk (one MFMA K=32 worth of fp16 pairs)
#define NCHUNK (KSLICE / BK)    // 32
#define NCHUNK_G (DIM / BK)     // 128 global chunks (pack kernel covers full K)

typedef _Float16 f16x8 __attribute__((ext_vector_type(8)));
typedef float    f32x4 __attribute__((ext_vector_type(4)));

#define MFMA16(a, b, c) __builtin_amdgcn_mfma_f32_16x16x32_f16((a), (b), (c), 0, 0, 0)
#define SBAR() __builtin_amdgcn_sched_barrier(0)

// ---------------- Kernel 0: pack W into MFMA B-fragments (fp16 hi/lo split) ----
// Layout: wpk[c=0..127][t=0..3][lane=0..63][2] x 16B frags (hi, lo).
// Fragment convention (must match A-side in the GEMM): lane l supplies
// B[k = 8*(l>>4)+j][n = l&15] for j=0..7. Any HW-internal k-permutation cancels
// because A uses the same convention. Lo part scaled by 2^16 so it stays
// fp16-normal; |w|<2^-14 guarded to 0 in hi so denormal-flush can't bite.
__global__ __launch_bounds__(256)
void pack_w_kernel(const float* __restrict__ w, uint4* __restrict__ wpk) {
    const int lane = threadIdx.x & 63;
    const int t    = threadIdx.x >> 6;     // expert tile 0..3
    const int c    = blockIdx.x;           // global k-chunk 0..127
    const int e    = 16 * t + (lane & 15);
    const int k0   = 32 * c + 8 * (lane >> 4);

    const float* src = w + (size_t)e * DIM + k0;
    const float4 v0 = *(const float4*)(src);
    const float4 v1 = *(const float4*)(src + 4);
    const float xs[8] = {v0.x, v0.y, v0.z, v0.w, v1.x, v1.y, v1.z, v1.w};

    f16x8 hi, lo;
#pragma unroll
    for (int j = 0; j < 8; ++j) {
        const float xv = xs[j];
        _Float16 h = (_Float16)xv;           // RNE
        float hf = (float)h;
        if (fabsf(xv) < 6.103515625e-05f) {  // below fp16 min normal: force hi=0
            h = (_Float16)0.f; hf = 0.f;
        }
        hi[j] = h;
        lo[j] = (_Float16)((xv - hf) * 65536.f);  // exact sub; scaled lo is normal
    }

    uint4* dst = wpk + ((size_t)(c * 4 + t) * 64 + lane) * 2;
    dst[0] = *(const uint4*)&hi;
    dst[1] = *(const uint4*)&lo;
}

// ---------------- Kernel 1: split-K router GEMM via fp16-split MFMA ----------
// grid 1024, block 256 (4 waves, no LDS/barriers). ks = bid&3: co-resident
// blocks (bid+=256) share one W k-slice -> B stream is L1/L2-resident.
//
// R3/R4: PIN the software pipeline with sched_barrier(0). R2's register
// double-buffer was destroyed by the scheduler (VGPR_Count=64 vs the ~130 the
// pipeline needs -> every refill load was sunk to just before its consume ->
// serial full-latency waits, MfmaUtil 6%, 964 GB/s). Structure per half-chunk:
//   split_a(xPing) ; issue X refill (2-chunk lead > ~900cy HBM latency)
//   12 MFMA consuming B set (loaded one half-chunk ago -> counted vmcnt wait,
//     L2-hit latency ~200cy hidden under 4 waves x ~170cy issue wall)
//   issue B refill <- next chunk
//   sched_barrier(0)   <- loads cannot sink below, computes cannot hoist above
// Single B register set (refill-after-consume): keeps VGPR ~100 <= 128 so all
// 4 blocks/CU stay resident under waves_per_eu(4,4).
// All prefetch indices wrap (&31 / ternary) -> strictly in-bounds accesses.
__device__ __forceinline__ void split_a(const float4 lo, const float4 hi,
                                        f16x8& ah, f16x8& al) {
    const float xs[8] = {lo.x, lo.y, lo.z, lo.w, hi.x, hi.y, hi.z, hi.w};
#pragma unroll
    for (int j = 0; j < 8; ++j) {
        const float xv = xs[j];
        const _Float16 h = (_Float16)xv;               // RNE
        ah[j] = h;
        al[j] = (_Float16)((xv - (float)h) * 65536.f); // exact sub, exact *2^16
    }
}

__device__ __forceinline__ void fma3(const f16x8 ah, const f16x8 al,
                                     const f16x8 bh, const f16x8 bl,
                                     f32x4& a1, f32x4& a2) {
    a1 = MFMA16(ah, bh, a1);   // hi*hi
    a2 = MFMA16(ah, bl, a2);   // hi*lo (scaled 2^16)
    a2 = MFMA16(al, bh, a2);   // lo*hi (scaled 2^16)
}

__global__ __launch_bounds__(256)
__attribute__((amdgpu_waves_per_eu(4, 4)))
void router_gemm_kernel(const float* __restrict__ x,
                        const f16x8* __restrict__ wpk,
                        float* __restrict__ part) {
    const int tid    = threadIdx.x;
    const int lane   = tid & 63;
    const int wv     = tid >> 6;
    const int bid    = blockIdx.x;
    const int ks     = bid & (KSPLIT - 1);
    const int tb     = bid >> 2;
    const int token0 = tb * 64 + wv * 16;

    // A side: lane l -> token row (l&15), k base 8*(l>>4) within the chunk
    const int row = token0 + (lane & 15);
    const float* xp = x + (size_t)row * DIM + ks * KSLICE + 8 * (lane >> 4);

    // B side: per-chunk stride 512 f16x8; tile stride 128; (hi,lo) adjacent
    const f16x8* bp = wpk + (size_t)ks * NCHUNK * 512 + lane * 2;

    f32x4 a10, a11, a12, a13, a20, a21, a22, a23;
    const f32x4 zero = {0.f, 0.f, 0.f, 0.f};
    a10 = a11 = a12 = a13 = zero;
    a20 = a21 = a22 = a23 = zero;

    // prologue: X chunks 0,1 (ping/pong); B chunk 0 (single set, all 4 tiles)
    float4 xAlo = *(const float4*)(xp);
    float4 xAhi = *(const float4*)(xp + 4);
    float4 xBlo = *(const float4*)(xp + BK);
    float4 xBhi = *(const float4*)(xp + BK + 4);
    f16x8 bh0 = bp[0],   bl0 = bp[1];
    f16x8 bh1 = bp[128], bl1 = bp[129];
    f16x8 bh2 = bp[256], bl2 = bp[257];
    f16x8 bh3 = bp[384], bl3 = bp[385];

    f16x8 ah, al;
#pragma unroll 1
    for (int c = 0; c < NCHUNK; c += 2) {
        // ---------------- half 1: consume chunk c (xA ping, B set) ----------
        split_a(xAlo, xAhi, ah, al);
        {   // X refill -> chunk c+2 (2-chunk lead; wrap keeps address legal)
            const int cn = (c + 2) & (NCHUNK - 1);
            xAlo = *(const float4*)(xp + cn * BK);
            xAhi = *(const float4*)(xp + cn * BK + 4);
        }
        fma3(ah, al, bh0, bl0, a10, a20);
        fma3(ah, al, bh1, bl1, a11, a21);
        fma3(ah, al, bh2, bl2, a12, a22);
        fma3(ah, al, bh3, bl3, a13, a23);
        {   // B refill <- chunk c+1 (consumed after the barrier, in half 2)
            const f16x8* pn = bp + (size_t)(c + 1) * 512;
            bh0 = pn[0];   bl0 = pn[1];
            bh1 = pn[128]; bl1 = pn[129];
            bh2 = pn[256]; bl2 = pn[257];
            bh3 = pn[384]; bl3 = pn[385];
        }
        SBAR();
        // ---------------- half 2: consume chunk c+1 (xB pong, B set) --------
        split_a(xBlo, xBhi, ah, al);
        {   // X refill -> chunk c+3
            const int cn = (c + 3) & (NCHUNK - 1);
            xBlo = *(const float4*)(xp + cn * BK);
            xBhi = *(const float4*)(xp + cn * BK + 4);
        }
        fma3(ah, al, bh0, bl0, a10, a20);
        fma3(ah, al, bh1, bl1, a11, a21);
        fma3(ah, al, bh2, bl2, a12, a22);
        fma3(ah, al, bh3, bl3, a13, a23);
        {   // B refill <- chunk (c+2)&31: wraps to 0 at the last iteration
            // (dead value there -- loop exits before consume), strictly
            // in-bounds so no reliance on workspace slack.
            const f16x8* pn = bp + (size_t)((c + 2) & (NCHUNK - 1)) * 512;
            bh0 = pn[0];   bl0 = pn[1];
            bh1 = pn[128]; bl1 = pn[129];
            bh2 = pn[256]; bl2 = pn[257];
            bh3 = pn[384]; bl3 = pn[385];
        }
        SBAR();
    }

    // Epilogue: D lane map (HW-verified): m = 4*(l>>4)+r, n = l&15.
    float* pout = part + ((size_t)ks * TOKENS + token0 + 4 * (lane >> 4)) * NEXP
                + (lane & 15);
    const f32x4 v0 = a10 + a20 * (1.f / 65536.f);
    const f32x4 v1 = a11 + a21 * (1.f / 65536.f);
    const f32x4 v2 = a12 + a22 * (1.f / 65536.f);
    const f32x4 v3 = a13 + a23 * (1.f / 65536.f);
#pragma unroll
    for (int r = 0; r < 4; ++r) {
        pout[(size_t)r * NEXP +  0] = v0[r];
        pout[(size_t)r * NEXP + 16] = v1[r];
        pout[(size_t)r * NEXP + 32] = v2[r];
        pout[(size_t)r * NEXP + 48] = v3[r];
    }
}

// ---------------- Kernel 2: split-K reduce + top-2 + softmax ----------------
// One wave per token; lane == expert. Butterfly argmax twice (tiebreak: lower
// index). Indices written as float (harness reads d_out via the fp32 path).
__global__ __launch_bounds__(256)
void topk_kernel(const float* __restrict__ part, float* __restrict__ out) {
    const int lane  = threadIdx.x & 63;
    const int wv    = threadIdx.x >> 6;
    const int token = blockIdx.x * 4 + wv;

    float logit = 0.f;
#pragma unroll
    for (int s = 0; s < KSPLIT; ++s)
        logit += part[((size_t)s * TOKENS + token) * NEXP + lane];

    // top-1
    float v1 = logit; int i1 = lane;
#pragma unroll
    for (int off = 32; off > 0; off >>= 1) {
        const float ov = __shfl_xor(v1, off);
        const int   oi = __shfl_xor(i1, off);
        if (ov > v1 || (ov == v1 && oi < i1)) { v1 = ov; i1 = oi; }
    }
    // top-2: mask the winner
    float v2 = (lane == i1) ? -INFINITY : logit; int i2 = lane;
#pragma unroll
    for (int off = 32; off > 0; off >>= 1) {
        const float ov = __shfl_xor(v2, off);
        const int   oi = __shfl_xor(i2, off);
        if (ov > v2 || (ov == v2 && oi < i2)) { v2 = ov; i2 = oi; }
    }

    if (lane == 0) {
        const float e = expf(v2 - v1);       // <= 1, no overflow
        const float r = 1.f / (1.f + e);
        out[2 * token + 0] = r;              // score of top-1
        out[2 * token + 1] = e * r;          // score of top-2
        out[2 * TOKENS + 2 * token + 0] = (float)i1;
        out[2 * TOKENS + 2 * token + 1] = (float)i2;
    }
}

extern "C" void kernel_launch(void* const* d_in, const int* in_sizes, int n_in,
                              void* d_out, int out_size, void* d_ws, size_t ws_size,
                              hipStream_t stream) {
    const float* x = (const float*)d_in[0];   // (4,4096,4096) fp32
    const float* w = (const float*)d_in[1];   // (64,4096) fp32
    float* out  = (float*)d_out;              // 32768 scores + 32768 float-encoded indices
    float* part = (float*)d_ws;               // KSPLIT*TOKENS*NEXP*4 = 16.8 MB
    // packed W fragments right after part: 128*4*64*2*16B = 1 MB
    uint4* wpk = (uint4*)((char*)d_ws + (size_t)KSPLIT * TOKENS * NEXP * sizeof(float));

    pack_w_kernel<<<NCHUNK_G, 256, 0, stream>>>(w, wpk);
    router_gemm_kernel<<<(TOKENS / 64) * KSPLIT, 256, 0, stream>>>(
        x, (const f16x8*)wpk, part);
    topk_kernel<<<TOKENS / 4, 256, 0, stream>>>(part, out);
}

// Round 5
// 380.325 us; speedup vs baseline: 1.1063x; 1.0743x over previous
//
#include <hip/hip_runtime.h>
#include <math.h>

#define TOKENS 16384
#define DIM    4096
#define NEXP   64
#define KSPLIT 4
#define KSLICE (DIM / KSPLIT)   // 1024
#define BK     32               // k per chunk (one MFMA K=32)
#define NCHUNK (KSLICE / BK)    // 32
#define NCHUNK_G (DIM / BK)     // 128 global chunks

typedef _Float16 f16x8 __attribute__((ext_vector_type(8)));
typedef float    f32x4 __attribute__((ext_vector_type(4)));

#define MFMA16(a, b, c) __builtin_amdgcn_mfma_f32_16x16x32_f16((a), (b), (c), 0, 0, 0)

// async global->LDS, 16B per lane, dest = wave-uniform base + 16*lane
__device__ __forceinline__ void gload16(const void* g, void* l) {
    __builtin_amdgcn_global_load_lds(
        (const __attribute__((address_space(1))) void*)g,
        (__attribute__((address_space(3))) void*)l, 16, 0, 0);
}

// ---------------- Kernel 0: pack W into MFMA B-fragment planes ---------------
// Layout: wpk[c=0..127][plane p=0..7][lane=0..63] x 16B. p = 2*t + h
// (t = expert tile, h = 0 hi / 1 lo). Plane = 1KB contiguous-by-lane, so the
// GEMM stages it with ONE perfectly-linear global_load_lds and reads it back
// as contiguous-by-lane ds_read_b128 (conflict-free).
// Fragment convention (matches A-side): lane l supplies B[k=8*(l>>4)+j][n=l&15],
// j=0..7, from expert row e=16t+(l&15). Lo scaled 2^16 (stays fp16-normal);
// |w|<2^-14 guarded into lo so denormal flush can't bite.
__global__ __launch_bounds__(256)
void pack_w_kernel(const float* __restrict__ w, uint4* __restrict__ wpk) {
    const int lane = threadIdx.x & 63;
    const int t    = threadIdx.x >> 6;     // expert tile 0..3
    const int c    = blockIdx.x;           // global k-chunk 0..127
    const int e    = 16 * t + (lane & 15);
    const int k0   = 32 * c + 8 * (lane >> 4);

    const float* src = w + (size_t)e * DIM + k0;
    const float4 v0 = *(const float4*)(src);
    const float4 v1 = *(const float4*)(src + 4);
    const float xs[8] = {v0.x, v0.y, v0.z, v0.w, v1.x, v1.y, v1.z, v1.w};

    f16x8 hi, lo;
#pragma unroll
    for (int j = 0; j < 8; ++j) {
        const float xv = xs[j];
        _Float16 h = (_Float16)xv;           // RNE
        float hf = (float)h;
        if (fabsf(xv) < 6.103515625e-05f) {  // below fp16 min normal: hi = 0
            h = (_Float16)0.f; hf = 0.f;
        }
        hi[j] = h;
        lo[j] = (_Float16)((xv - hf) * 65536.f);
    }

    wpk[(size_t)c * 512 + (2 * t + 0) * 64 + lane] = *(const uint4*)&hi;
    wpk[(size_t)c * 512 + (2 * t + 1) * 64 + lane] = *(const uint4*)&lo;
}

// ---------------- Kernel 1: split-K router GEMM, LDS-staged (T3 pattern) -----
// grid 1024, block 256 (4 waves). ks = bid&3 -> co-resident blocks share one
// W k-slice (L2-resident B stream).
//
// R5: pipeline state moved from registers to LDS via global_load_lds. R2/R4
// showed register pipelines are destroyed or neutered by the scheduler, and
// the in-order vmcnt queue couples every B-fragment wait to outstanding X HBM
// misses. Now: per chunk each wave issues 4 gload_lds (2 X planes + 2 B
// planes) into the next LDS buffer, then ONE counted s_waitcnt vmcnt(4)
// (never 0) + raw s_barrier, then consumes the current buffer via ds_read.
// Lead = one full iteration (~HBM-paced 3+k cy >> ~900 cy latency),
// self-regulating.
//   X LDS layout (per wave, 2KB/chunk): row-major 16x32 f32 with 16B-block
//   swizzle blk ^= (row&7), pre-applied on the GLOBAL source (linear dest,
//   inverse-swizzled src, swizzled read) -> stage = 8 rows x 128B contiguous,
//   frag ds_read_b128 2-way max conflicts (free).
//   B LDS layout: 8 lane-planes, verbatim wpk chunk -> linear stage,
//   contiguous-by-lane reads.
// No __syncthreads anywhere (avoids the vmcnt(0) barrier drain).
__device__ __forceinline__ void split_a(const f32x4 lo, const f32x4 hi,
                                        f16x8& ah, f16x8& al) {
    const float xs[8] = {lo[0], lo[1], lo[2], lo[3], hi[0], hi[1], hi[2], hi[3]};
#pragma unroll
    for (int j = 0; j < 8; ++j) {
        const float xv = xs[j];
        const _Float16 h = (_Float16)xv;               // RNE
        ah[j] = h;
        al[j] = (_Float16)((xv - (float)h) * 65536.f); // exact sub, exact *2^16
    }
}

__device__ __forceinline__ void fma3(const f16x8 ah, const f16x8 al,
                                     const f16x8 bh, const f16x8 bl,
                                     f32x4& a1, f32x4& a2) {
    a1 = MFMA16(ah, bh, a1);   // hi*hi
    a2 = MFMA16(ah, bl, a2);   // hi*lo (scaled 2^16)
    a2 = MFMA16(al, bh, a2);   // lo*hi (scaled 2^16)
}

__global__ __launch_bounds__(256)
__attribute__((amdgpu_waves_per_eu(4, 4)))
void router_gemm_kernel(const float* __restrict__ x,
                        const uint4* __restrict__ wpk,
                        float* __restrict__ part) {
    // 2 buffers x (X 8KB + B 8KB) = 32KB
    __shared__ uint4 lds[2048];

    const int tid  = threadIdx.x;
    const int lane = tid & 63;
    const int wv   = tid >> 6;              // wave 0..3 (uniform)
    const int bid  = blockIdx.x;
    const int ks   = bid & (KSPLIT - 1);    // co-resident blocks share ks
    const int tb   = bid >> 2;
    const int wt0  = tb * 64 + wv * 16;     // wave's first token

    // ---- stage-side addressing (per lane) ----
    // X: instr q covers rows 8q..8q+7 of the wave; lane l -> row rl = l>>3,
    // 16B-block sb = (l&7) ^ rl (inverse swizzle), full 128B/row coverage.
    const int rl = lane >> 3;
    const int sb = (lane & 7) ^ rl;
    const float* xsrc0 = x + (size_t)(wt0 + rl)     * DIM + ks * KSLICE + 4 * sb;
    const float* xsrc1 = x + (size_t)(wt0 + 8 + rl) * DIM + ks * KSLICE + 4 * sb;
    // B: wave wv stages planes 2wv, 2wv+1; per-lane contiguous 16B.
    const uint4* bsrc = wpk + (size_t)(ks * NCHUNK) * 512 + (2 * wv) * 64 + lane;

    // ---- consume-side addressing ----
    const int r  = lane & 15;               // token row within wave
    const int kb = 2 * (lane >> 4);         // first 16B-block of A-frag
    const int xi0 = r * 8 + ((kb    ) ^ (r & 7));   // uint4 idx in wave X region
    const int xi1 = r * 8 + ((kb + 1) ^ (r & 7));

    f32x4 a10, a11, a12, a13, a20, a21, a22, a23;
    const f32x4 zero = {0.f, 0.f, 0.f, 0.f};
    a10 = a11 = a12 = a13 = zero;
    a20 = a21 = a22 = a23 = zero;

    // ---- stage helper: chunk cc -> buffer bsel ----
    auto STAGE = [&](int cc, int bsel) {
        uint4* Xb = &lds[bsel * 1024 + wv * 128];
        uint4* Bb = &lds[bsel * 1024 + 512 + (2 * wv) * 64];
        gload16(xsrc0 + cc * BK,            Xb);        // X plane q=0 (rows 0-7)
        gload16(xsrc1 + cc * BK,            Xb + 64);   // X plane q=1 (rows 8-15)
        gload16(bsrc + (size_t)cc * 512,      Bb);      // B plane 2wv
        gload16(bsrc + (size_t)cc * 512 + 64, Bb + 64); // B plane 2wv+1
    };

    STAGE(0, 0);   // prologue

#pragma unroll 1
    for (int c = 0; c < NCHUNK; ++c) {
        STAGE((c + 1) & (NCHUNK - 1), (c + 1) & 1);   // 4 gload_lds (in-bounds wrap)

        asm volatile("s_waitcnt vmcnt(4)" ::: "memory");   // chunk c staged; c+1 in flight
        __builtin_amdgcn_s_barrier();                      // all waves' stages visible

        const uint4* Xr = &lds[(c & 1) * 1024 + wv * 128];
        const uint4* Br = &lds[(c & 1) * 1024 + 512];

        const f32x4 xlo = *(const f32x4*)&Xr[xi0];
        const f32x4 xhi = *(const f32x4*)&Xr[xi1];
        const f16x8 bh0 = *(const f16x8*)&Br[0 * 64 + lane];
        const f16x8 bl0 = *(const f16x8*)&Br[1 * 64 + lane];
        const f16x8 bh1 = *(const f16x8*)&Br[2 * 64 + lane];
        const f16x8 bl1 = *(const f16x8*)&Br[3 * 64 + lane];
        const f16x8 bh2 = *(const f16x8*)&Br[4 * 64 + lane];
        const f16x8 bl2 = *(const f16x8*)&Br[5 * 64 + lane];
        const f16x8 bh3 = *(const f16x8*)&Br[6 * 64 + lane];
        const f16x8 bl3 = *(const f16x8*)&Br[7 * 64 + lane];

        f16x8 ah, al;
        split_a(xlo, xhi, ah, al);
        fma3(ah, al, bh0, bl0, a10, a20);
        fma3(ah, al, bh1, bl1, a11, a21);
        fma3(ah, al, bh2, bl2, a12, a22);
        fma3(ah, al, bh3, bl3, a13, a23);

        asm volatile("s_waitcnt lgkmcnt(0)" ::: "memory"); // my ds_reads done
        __builtin_amdgcn_s_barrier();                      // safe to overwrite buf
    }

    // Epilogue: D lane map (HW-verified): m = 4*(l>>4)+rr, n = l&15.
    float* pout = part + ((size_t)ks * TOKENS + wt0 + 4 * (lane >> 4)) * NEXP
                + (lane & 15);
    const f32x4 v0 = a10 + a20 * (1.f / 65536.f);
    const f32x4 v1 = a11 + a21 * (1.f / 65536.f);
    const f32x4 v2 = a12 + a22 * (1.f / 65536.f);
    const f32x4 v3 = a13 + a23 * (1.f / 65536.f);
#pragma unroll
    for (int rr = 0; rr < 4; ++rr) {
        pout[(size_t)rr * NEXP +  0] = v0[rr];
        pout[(size_t)rr * NEXP + 16] = v1[rr];
        pout[(size_t)rr * NEXP + 32] = v2[rr];
        pout[(size_t)rr * NEXP + 48] = v3[rr];
    }
}

// ---------------- Kernel 2: split-K reduce + top-2 + softmax ----------------
// One wave per token; lane == expert. Butterfly argmax twice (tiebreak: lower
// index). Indices written as float (harness reads d_out via the fp32 path).
__global__ __launch_bounds__(256)
void topk_kernel(const float* __restrict__ part, float* __restrict__ out) {
    const int lane  = threadIdx.x & 63;
    const int wv    = threadIdx.x >> 6;
    const int token = blockIdx.x * 4 + wv;

    float logit = 0.f;
#pragma unroll
    for (int s = 0; s < KSPLIT; ++s)
        logit += part[((size_t)s * TOKENS + token) * NEXP + lane];

    // top-1
    float v1 = logit; int i1 = lane;
#pragma unroll
    for (int off = 32; off > 0; off >>= 1) {
        const float ov = __shfl_xor(v1, off);
        const int   oi = __shfl_xor(i1, off);
        if (ov > v1 || (ov == v1 && oi < i1)) { v1 = ov; i1 = oi; }
    }
    // top-2: mask the winner
    float v2 = (lane == i1) ? -INFINITY : logit; int i2 = lane;
#pragma unroll
    for (int off = 32; off > 0; off >>= 1) {
        const float ov = __shfl_xor(v2, off);
        const int   oi = __shfl_xor(i2, off);
        if (ov > v2 || (ov == v2 && oi < i2)) { v2 = ov; i2 = oi; }
    }

    if (lane == 0) {
        const float e = expf(v2 - v1);       // <= 1, no overflow
        const float r = 1.f / (1.f + e);
        out[2 * token + 0] = r;              // score of top-1
        out[2 * token + 1] = e * r;          // score of top-2
        out[2 * TOKENS + 2 * token + 0] = (float)i1;
        out[2 * TOKENS + 2 * token + 1] = (float)i2;
    }
}

extern "C" void kernel_launch(void* const* d_in, const int* in_sizes, int n_in,
                              void* d_out, int out_size, void* d_ws, size_t ws_size,
                              hipStream_t stream) {
    const float* x = (const float*)d_in[0];   // (4,4096,4096) fp32
    const float* w = (const float*)d_in[1];   // (64,4096) fp32
    float* out  = (float*)d_out;              // 32768 scores + 32768 float-encoded indices
    float* part = (float*)d_ws;               // KSPLIT*TOKENS*NEXP*4 = 16.8 MB
    // packed W fragment planes right after part: 128*8*64*16B = 1 MB
    uint4* wpk = (uint4*)((char*)d_ws + (size_t)KSPLIT * TOKENS * NEXP * sizeof(float));

    pack_w_kernel<<<NCHUNK_G, 256, 0, stream>>>(w, wpk);
    router_gemm_kernel<<<(TOKENS / 64) * KSPLIT, 256, 0, stream>>>(x, wpk, part);
    topk_kernel<<<TOKENS / 4, 256, 0, stream>>>(part, out);
}